// Round 1
// baseline (253.666 us; speedup 1.0000x reference)
//
#include <hip/hip_runtime.h>
#include <math.h>

#define BB 32
#define HH 128
#define WW 128
#define NA 9
#define CCH 46
#define NPIX (HH*WW)
#define STRIDE_F 16.0f
#define CLS_T 0.95f
#define MAX_IOU_F 0.1f
#define NUM_PROP 10
#define NEGV -1000000000.0f

// ---------------- decode + compact candidates ----------------
__global__ __launch_bounds__(256) void decode_kernel(
    const float* __restrict__ in, const float* __restrict__ anchors,
    int* __restrict__ counts, float* __restrict__ sc_comp,
    float4* __restrict__ co_comp, float4* __restrict__ bx_comp, int cap)
{
  int g = blockIdx.x * 256 + threadIdx.x;          // global pixel id
  int b = g >> 14;                                  // / 16384
  int p = g & (NPIX - 1);
  int h = p >> 7;
  int w = p & (WW - 1);
  const float* px = in + (size_t)g * CCH;

  float cls = px[45];
  bool interior = (h >= 1) && (h <= HH - 2) && (w >= 1) && (w <= WW - 2);
  bool cand = interior && (cls > CLS_T);

  unsigned long long mask = __ballot(cand);         // full-wave convergent point
  if (!cand) return;

  // argmax over 9 anchor logits (first-index tie-break via strict >)
  int ai = 0; float av = px[36];
#pragma unroll
  for (int c = 1; c < NA; ++c) { float v = px[36 + c]; if (v > av) { av = v; ai = c; } }

  float d0 = px[ai * 4 + 0], d1 = px[ai * 4 + 1];
  float d2 = px[ai * 4 + 2], d3 = px[ai * 4 + 3];
  float ratio = anchors[ai * 2 + 0], sz = anchors[ai * 2 + 1];
  float a2 = sz, a3 = sz / ratio;
  float ax = ((float)w + 0.5f) * STRIDE_F;
  float ay = ((float)h + 0.5f) * STRIDE_F;
  float b0 = d0 * a2 + ax;
  float b1 = d1 * a3 + ay;
  float b2 = expf(d2) * a2;
  float b3 = expf(d3) * a3;
  float4 box = make_float4(b0, b1, b2, b3);
  float4 co  = make_float4(b1 - 0.5f * b3, b0 - 0.5f * b2,
                           b1 + 0.5f * b3, b0 + 0.5f * b2);   // (y1,x1,y2,x2)

  // wave-aggregated slot allocation: one atomic per wave
  int lane = threadIdx.x & 63;
  int prefix = __popcll(mask & ((1ull << lane) - 1ull));
  int leader = __ffsll((unsigned long long)mask) - 1;
  int total = __popcll(mask);
  int base = 0;
  if (lane == leader) base = atomicAdd(&counts[b], total);
  base = __shfl(base, leader);
  int slot = base + prefix;
  if (slot < cap) {
    sc_comp[b * cap + slot] = cls;
    co_comp[b * cap + slot] = co;
    bx_comp[b * cap + slot] = box;
  }
}

// ---------------- per-batch sequential NMS ----------------
__global__ __launch_bounds__(256) void nms_kernel(
    const int* __restrict__ counts, const float* __restrict__ sc_comp,
    const float4* __restrict__ co_comp, const float4* __restrict__ bx_comp,
    float* __restrict__ out, int cap)
{
  __shared__ float s_sc[16384];    // 64 KB: scores live in LDS
  __shared__ float s_val[256];
  __shared__ int   s_idx[256];

  int b = blockIdx.x;
  int tid = threadIdx.x;
  int M = counts[b];
  if (M > cap) M = cap;

  for (int k = tid; k < M; k += 256) s_sc[k] = sc_comp[b * cap + k];
  __syncthreads();

  for (int it = 0; it < NUM_PROP; ++it) {
    // local argmax (lower index wins ties)
    float best = -INFINITY; int bidx = 0x7fffffff;
    for (int k = tid; k < M; k += 256) {
      float v = s_sc[k];
      if (v > best) { best = v; bidx = k; }
    }
    s_val[tid] = best; s_idx[tid] = bidx;
    __syncthreads();
    for (int s = 128; s > 0; s >>= 1) {
      if (tid < s) {
        float ov = s_val[tid + s]; int oi = s_idx[tid + s];
        if (ov > s_val[tid] || (ov == s_val[tid] && oi < s_idx[tid])) {
          s_val[tid] = ov; s_idx[tid] = oi;
        }
      }
      __syncthreads();
    }
    int j = s_idx[0];
    float jv = s_val[0];
    bool ok = (M > 0) && (jv > NEGV * 0.5f);

    if (ok) {
      float4 selc = co_comp[b * cap + j];           // broadcast load
      float area_s = fmaxf(selc.z - selc.x, 0.f) * fmaxf(selc.w - selc.y, 0.f);
      for (int k = tid; k < M; k += 256) {
        float4 c = co_comp[b * cap + k];
        float area = fmaxf(c.z - c.x, 0.f) * fmaxf(c.w - c.y, 0.f);
        float iy1 = fmaxf(c.x, selc.x);
        float ix1 = fmaxf(c.y, selc.y);
        float iy2 = fminf(c.z, selc.z);
        float ix2 = fminf(c.w, selc.w);
        float inter = fmaxf(iy2 - iy1, 0.f) * fmaxf(ix2 - ix1, 0.f);
        float iou = inter / (area + area_s - inter + 1e-10f);
        if (iou > MAX_IOU_F || k == j) s_sc[k] = NEGV;
      }
      if (tid == 0) {
        float4 bx = bx_comp[b * cap + j];
        float* o = out + (size_t)(b * NUM_PROP + it) * 4;
        o[0] = bx.x; o[1] = bx.y; o[2] = bx.z; o[3] = bx.w;
      }
    } else if (tid == 0) {
      float* o = out + (size_t)(b * NUM_PROP + it) * 4;
      o[0] = 0.f; o[1] = 0.f; o[2] = 0.f; o[3] = 0.f;
    }
    __syncthreads();
  }
}

extern "C" void kernel_launch(void* const* d_in, const int* in_sizes, int n_in,
                              void* d_out, int out_size, void* d_ws, size_t ws_size,
                              hipStream_t stream) {
  const float* in      = (const float*)d_in[0];
  const float* anchors = (const float*)d_in[1];
  float* out = (float*)d_out;

  // workspace layout: [counts: 256B pad][scores: B*cap f32][coords: B*cap f4][boxes: B*cap f4]
  char* ws = (char*)d_ws;
  int* counts = (int*)ws;
  size_t off = 256;
  size_t avail = (ws_size > off) ? (ws_size - off) : 0;
  long long cap_ll = (long long)(avail / ((size_t)BB * 36));
  int cap = (int)((cap_ll > NPIX) ? NPIX : cap_ll);
  if (cap < 1) cap = 1;  // degenerate-ws guard

  float*  sc_comp = (float*)(ws + off);
  size_t sc_bytes = (size_t)BB * cap * 4;
  size_t co_off = (off + sc_bytes + 15) & ~(size_t)15;
  float4* co_comp = (float4*)(ws + co_off);
  size_t co_bytes = (size_t)BB * cap * 16;
  size_t bx_off = (co_off + co_bytes + 15) & ~(size_t)15;
  float4* bx_comp = (float4*)(ws + bx_off);

  hipMemsetAsync(d_ws, 0, 256, stream);   // zero candidate counters

  decode_kernel<<<(BB * NPIX) / 256, 256, 0, stream>>>(
      in, anchors, counts, sc_comp, co_comp, bx_comp, cap);
  nms_kernel<<<BB, 256, 0, stream>>>(
      counts, sc_comp, co_comp, bx_comp, out, cap);
}